// Round 11
// baseline (436.764 us; speedup 1.0000x reference)
//
#include <hip/hip_runtime.h>

namespace {
constexpr int NN = 100000;
constexpr int NE = 600000;
constexpr int H  = 128;
constexpr int SCAN_B = 256;
constexpr int NBLK_SCAN = (NN + SCAN_B - 1) / SCAN_B;  // 391
constexpr int NROWBLK256 = (NN + 255) / 256;           // 391

__global__ __launch_bounds__(256) void write_marker(float* __restrict__ out,
                                                    int n, float val) {
  int i = blockIdx.x * 256 + threadIdx.x;
  if (i < n) out[i] = val;
}

// ---------------- bottom-tier fallback (atomic path, verified) ----------------

__global__ __launch_bounds__(256) void zero_f4(float4* __restrict__ p, int n4) {
  int i = blockIdx.x * 256 + threadIdx.x;
  if (i < n4) p[i] = float4{0.f, 0.f, 0.f, 0.f};
}

__global__ __launch_bounds__(256) void scatter_l1(
    const int* __restrict__ src, const int* __restrict__ dst,
    const int* __restrict__ node_id, const float* __restrict__ embed,
    const float* __restrict__ norm, float* __restrict__ agg) {
  int idx = blockIdx.x * 256 + threadIdx.x;
  int e = idx >> 5;
  if (e >= NE) return;
  int c = (idx & 31) << 2;
  int s = src[e];
  float nrm = norm[s];
  const float4 v = *reinterpret_cast<const float4*>(embed + (size_t)node_id[s] * H + c);
  float* o = agg + (size_t)dst[e] * H + c;
  atomicAdd(o + 0, v.x * nrm);
  atomicAdd(o + 1, v.y * nrm);
  atomicAdd(o + 2, v.z * nrm);
  atomicAdd(o + 3, v.w * nrm);
}

__global__ __launch_bounds__(256) void scatter_l2(
    const int* __restrict__ src, const int* __restrict__ dst,
    const float* __restrict__ h1, const float* __restrict__ norm,
    float* __restrict__ agg) {
  int idx = blockIdx.x * 256 + threadIdx.x;
  int e = idx >> 5;
  if (e >= NE) return;
  int c = (idx & 31) << 2;
  int s = src[e];
  float nrm = norm[s];
  const float4 v = *reinterpret_cast<const float4*>(h1 + (size_t)s * H + c);
  float* o = agg + (size_t)dst[e] * H + c;
  atomicAdd(o + 0, v.x * nrm);
  atomicAdd(o + 1, v.y * nrm);
  atomicAdd(o + 2, v.z * nrm);
  atomicAdd(o + 3, v.w * nrm);
}

__global__ __launch_bounds__(128) void row_gemm_act(
    const float* __restrict__ agg, const float* __restrict__ W,
    const float* __restrict__ norm, const float* __restrict__ bias,
    float* __restrict__ out) {
  __shared__ float hs[H];
  const int row = blockIdx.x, j = threadIdx.x;
  hs[j] = agg[(size_t)row * H + j];
  __syncthreads();
  float acc = 0.f;
#pragma unroll
  for (int k = 0; k < H; ++k) acc += hs[k] * W[k * H + j];
  float v = acc * norm[row] + bias[j];
  v = v > 0.f ? v : 0.2f * v;
  out[(size_t)row * H + j] = v;
}

// ---------------- CSR build ----------------

__global__ __launch_bounds__(256) void zero_int(int* __restrict__ p, int n) {
  int i = blockIdx.x * 256 + threadIdx.x;
  if (i < n) p[i] = 0;
}

__global__ __launch_bounds__(256) void hist_dst(const int* __restrict__ dst,
                                                int* __restrict__ deg) {
  int e = blockIdx.x * 256 + threadIdx.x;
  if (e < NE) atomicAdd(&deg[dst[e]], 1);
}

__global__ __launch_bounds__(SCAN_B) void scan1(const int* __restrict__ deg,
                                                int* __restrict__ offs,
                                                int* __restrict__ bsums) {
  __shared__ int sh[SCAN_B];
  const int t = threadIdx.x;
  const int gid = blockIdx.x * SCAN_B + t;
  int v = (gid < NN) ? deg[gid] : 0;
  sh[t] = v;
  __syncthreads();
  for (int d = 1; d < SCAN_B; d <<= 1) {
    int add = (t >= d) ? sh[t - d] : 0;
    __syncthreads();
    sh[t] += add;
    __syncthreads();
  }
  if (gid < NN) offs[gid] = sh[t] - v;
  if (t == SCAN_B - 1) bsums[blockIdx.x] = sh[t];
}

__global__ __launch_bounds__(512) void scan2(int* __restrict__ bsums) {
  __shared__ int sh[512];
  const int t = threadIdx.x;
  int v = (t < NBLK_SCAN) ? bsums[t] : 0;
  sh[t] = v;
  __syncthreads();
  for (int d = 1; d < 512; d <<= 1) {
    int add = (t >= d) ? sh[t - d] : 0;
    __syncthreads();
    sh[t] += add;
    __syncthreads();
  }
  if (t < NBLK_SCAN) bsums[t] = sh[t] - v;
}

// finalize offs AND seed cnt = offs (fill uses cnt as running cursor)
__global__ __launch_bounds__(256) void scan3(int* __restrict__ offs,
                                             const int* __restrict__ bsums,
                                             int* __restrict__ cnt) {
  int gid = blockIdx.x * 256 + threadIdx.x;
  if (gid < NN) {
    int v = offs[gid] + bsums[blockIdx.x];
    offs[gid] = v;
    cnt[gid] = v;
  }
  if (gid == 0) offs[NN] = NE;
}

template <bool WITH_REC>
__global__ __launch_bounds__(256) void fill_csr(
    const int* __restrict__ src, const int* __restrict__ dst,
    const int* __restrict__ node_id, const float* __restrict__ norm,
    int* __restrict__ cnt, int* __restrict__ csr2, int2* __restrict__ rec1) {
  int e = blockIdx.x * 256 + threadIdx.x;
  if (e >= NE) return;
  int d = dst[e];
  int s = src[e];
  int pos = atomicAdd(&cnt[d], 1);
  csr2[pos] = s;
  if (WITH_REC) rec1[pos] = make_int2(node_id[s], __float_as_int(norm[s]));
}

// ---------------- gathers (no atomics; 4-way independent chains for MLP) ----------------

// L1: per-edge record {row, nrm}; 32 lanes per node, float4/lane.
__global__ __launch_bounds__(256) void gather_rec(
    const int* __restrict__ offs, const int2* __restrict__ rec,
    const float* __restrict__ h, float* __restrict__ agg) {
  const int node = blockIdx.x * 8 + (threadIdx.x >> 5);
  const int c = (threadIdx.x & 31) << 2;
  const int beg = offs[node];
  const int end = offs[node + 1];
  float4 a0{0,0,0,0}, a1{0,0,0,0}, a2{0,0,0,0}, a3{0,0,0,0};
  int i = beg;
  for (; i + 4 <= end; i += 4) {
    int2 r0 = rec[i], r1 = rec[i + 1], r2 = rec[i + 2], r3 = rec[i + 3];
    const float4 v0 = *reinterpret_cast<const float4*>(h + (size_t)r0.x * H + c);
    const float4 v1 = *reinterpret_cast<const float4*>(h + (size_t)r1.x * H + c);
    const float4 v2 = *reinterpret_cast<const float4*>(h + (size_t)r2.x * H + c);
    const float4 v3 = *reinterpret_cast<const float4*>(h + (size_t)r3.x * H + c);
    float n0 = __int_as_float(r0.y), n1 = __int_as_float(r1.y);
    float n2 = __int_as_float(r2.y), n3 = __int_as_float(r3.y);
    a0.x += v0.x * n0; a0.y += v0.y * n0; a0.z += v0.z * n0; a0.w += v0.w * n0;
    a1.x += v1.x * n1; a1.y += v1.y * n1; a1.z += v1.z * n1; a1.w += v1.w * n1;
    a2.x += v2.x * n2; a2.y += v2.y * n2; a2.z += v2.z * n2; a2.w += v2.w * n2;
    a3.x += v3.x * n3; a3.y += v3.y * n3; a3.z += v3.z * n3; a3.w += v3.w * n3;
  }
  for (; i < end; ++i) {
    int2 r0 = rec[i];
    const float4 v0 = *reinterpret_cast<const float4*>(h + (size_t)r0.x * H + c);
    float n0 = __int_as_float(r0.y);
    a0.x += v0.x * n0; a0.y += v0.y * n0; a0.z += v0.z * n0; a0.w += v0.w * n0;
  }
  a0.x += a1.x + a2.x + a3.x;
  a0.y += a1.y + a2.y + a3.y;
  a0.z += a1.z + a2.z + a3.z;
  a0.w += a1.w + a2.w + a3.w;
  *reinterpret_cast<float4*>(agg + (size_t)node * H + c) = a0;
}

// L2: h is pre-scaled by norm (h1n), so just sum rows.
__global__ __launch_bounds__(256) void gather_idx(
    const int* __restrict__ offs, const int* __restrict__ csr,
    const float* __restrict__ h, float* __restrict__ agg) {
  const int node = blockIdx.x * 8 + (threadIdx.x >> 5);
  const int c = (threadIdx.x & 31) << 2;
  const int beg = offs[node];
  const int end = offs[node + 1];
  float4 a0{0,0,0,0}, a1{0,0,0,0}, a2{0,0,0,0}, a3{0,0,0,0};
  int i = beg;
  for (; i + 4 <= end; i += 4) {
    int s0 = csr[i], s1 = csr[i + 1], s2 = csr[i + 2], s3 = csr[i + 3];
    const float4 v0 = *reinterpret_cast<const float4*>(h + (size_t)s0 * H + c);
    const float4 v1 = *reinterpret_cast<const float4*>(h + (size_t)s1 * H + c);
    const float4 v2 = *reinterpret_cast<const float4*>(h + (size_t)s2 * H + c);
    const float4 v3 = *reinterpret_cast<const float4*>(h + (size_t)s3 * H + c);
    a0.x += v0.x; a0.y += v0.y; a0.z += v0.z; a0.w += v0.w;
    a1.x += v1.x; a1.y += v1.y; a1.z += v1.z; a1.w += v1.w;
    a2.x += v2.x; a2.y += v2.y; a2.z += v2.z; a2.w += v2.w;
    a3.x += v3.x; a3.y += v3.y; a3.z += v3.z; a3.w += v3.w;
  }
  for (; i < end; ++i) {
    int s0 = csr[i];
    const float4 v0 = *reinterpret_cast<const float4*>(h + (size_t)s0 * H + c);
    a0.x += v0.x; a0.y += v0.y; a0.z += v0.z; a0.w += v0.w;
  }
  a0.x += a1.x + a2.x + a3.x;
  a0.y += a1.y + a2.y + a3.y;
  a0.z += a1.z + a2.z + a3.z;
  a0.w += a1.w + a2.w + a3.w;
  *reinterpret_cast<float4*>(agg + (size_t)node * H + c) = a0;
}

// mid-tier L1 gather (no records): loads node_id/norm per edge
__global__ __launch_bounds__(256) void gather_mid_l1(
    const int* __restrict__ offs, const int* __restrict__ csr,
    const int* __restrict__ node_id, const float* __restrict__ h,
    const float* __restrict__ norm, float* __restrict__ agg) {
  const int node = blockIdx.x * 8 + (threadIdx.x >> 5);
  const int c = (threadIdx.x & 31) << 2;
  const int beg = offs[node];
  const int end = offs[node + 1];
  float4 acc{0.f, 0.f, 0.f, 0.f};
  for (int i = beg; i < end; ++i) {
    int s = csr[i];
    float nrm = norm[s];
    const float4 v = *reinterpret_cast<const float4*>(h + (size_t)node_id[s] * H + c);
    acc.x += v.x * nrm; acc.y += v.y * nrm; acc.z += v.z * nrm; acc.w += v.w * nrm;
  }
  *reinterpret_cast<float4*>(agg + (size_t)node * H + c) = acc;
}

// ---------------- GEMM v8: 256 rows x 64 cols, 8 rows/thread ----------------
// v7 post-mortem (r10): 54.5 us, VALUBusy 49%. Wall = LDS READ THROUGHPUT:
// per k4 each wave issues 8 ds_read_b128 (~96 LDS-unit cyc) vs only 256 FMA
// SIMD-cyc; whole-layer LDS demand ~31 us/layer > 20.8 us FMA floor. Only
// rows/thread amortizes W-reads (W is shared across rows). v8: 8 rows/thread
// (thread tile 8x8): same 8 W-reads per k4 but 512 FMA cyc -> LDS demand
// ~15.6 us < FMA 20.8 us -> VALU-bound. VGPR ~150 (16 acc + 8 A + 8 W float4
// + addr); __launch_bounds__(256,2) caps 256 -> NO forced spill (r5 lesson);
// 3 waves/SIMD, LDS 32 KB allows 5 blocks/CU. acc arrays fully unrolled
// (static idx, rule #20). FMA order per output unchanged => same numerics.

#define FMA4(ACC, S, W) \
  ACC.x += (S) * (W).x; ACC.y += (S) * (W).y; ACC.z += (S) * (W).z; ACC.w += (S) * (W).w;

// out[row] = LReLU((agg[row] @ W) * norm[row] + b) * (SCALE_OUT ? norm[row] : 1)
template <bool SCALE_OUT>
__global__ __launch_bounds__(256, 2) void gemm_v8(
    const float* __restrict__ agg, const float* __restrict__ W,
    const float* __restrict__ norm, const float* __restrict__ bias,
    float* __restrict__ out) {
  __shared__ float4 Wld[128 * 16];  // 32 KB: [k][c], c=0..15 -> col half*64+c*4
  const int t = threadIdx.x;
  const int half = blockIdx.x & 1;            // column half (0: cols 0-63, 1: 64-127)
  const int rowBase = (blockIdx.x >> 1) * 256;

  // stage W half: 2048 float4, 8 per thread
  const float4* W4 = reinterpret_cast<const float4*>(W);
#pragma unroll
  for (int i = 0; i < 8; ++i) {
    int g = t + i * 256;            // 0..2047
    int k = g >> 4, c = g & 15;
    Wld[k * 16 + c] = W4[k * 32 + half * 16 + c];
  }
  __syncthreads();

  const int j8 = t & 7;    // col group of 8 within half
  const int r0 = t >> 3;   // 0..31; rows r0 + 32*i, i=0..7
  const float4* A4 = reinterpret_cast<const float4*>(agg) + (size_t)rowBase * 32;

  float4 accA[8], accB[8];
#pragma unroll
  for (int i = 0; i < 8; ++i) {
    accA[i] = float4{0.f, 0.f, 0.f, 0.f};
    accB[i] = float4{0.f, 0.f, 0.f, 0.f};
  }

  // NOTE: last row-block reads A rows up to 100095 (> NN); those land inside
  // the allocated workspace (CSR arrays follow agg in BOTH tiers: mid-tier
  // floor 53.6 MB > 51.25 MB max touched) so reads are safe; outputs are
  // guarded at the store.
#pragma unroll 2
  for (int k4 = 0; k4 < 32; ++k4) {
    float4 a[8];
#pragma unroll
    for (int i = 0; i < 8; ++i) a[i] = A4[(r0 + 32 * i) * 32 + k4];
    const int kb = k4 * 64;  // (4*k4) * 16
    float4 wa0 = Wld[kb + 2 * j8],      wb0 = Wld[kb + 2 * j8 + 1];
    float4 wa1 = Wld[kb + 16 + 2 * j8], wb1 = Wld[kb + 16 + 2 * j8 + 1];
    float4 wa2 = Wld[kb + 32 + 2 * j8], wb2 = Wld[kb + 32 + 2 * j8 + 1];
    float4 wa3 = Wld[kb + 48 + 2 * j8], wb3 = Wld[kb + 48 + 2 * j8 + 1];
#pragma unroll
    for (int i = 0; i < 8; ++i) {
      FMA4(accA[i], a[i].x, wa0) FMA4(accB[i], a[i].x, wb0)
      FMA4(accA[i], a[i].y, wa1) FMA4(accB[i], a[i].y, wb1)
      FMA4(accA[i], a[i].z, wa2) FMA4(accB[i], a[i].z, wb2)
      FMA4(accA[i], a[i].w, wa3) FMA4(accB[i], a[i].w, wb3)
    }
  }

  const float4 bv0 = reinterpret_cast<const float4*>(bias)[half * 16 + 2 * j8];
  const float4 bv1 = reinterpret_cast<const float4*>(bias)[half * 16 + 2 * j8 + 1];
#pragma unroll
  for (int i = 0; i < 8; ++i) {
    const int row = rowBase + r0 + 32 * i;
    if (row < NN) {
      const float nrm = norm[row];
      float4 o0, o1;
      o0.x = accA[i].x * nrm + bv0.x; o0.y = accA[i].y * nrm + bv0.y;
      o0.z = accA[i].z * nrm + bv0.z; o0.w = accA[i].w * nrm + bv0.w;
      o1.x = accB[i].x * nrm + bv1.x; o1.y = accB[i].y * nrm + bv1.y;
      o1.z = accB[i].z * nrm + bv1.z; o1.w = accB[i].w * nrm + bv1.w;
      o0.x = o0.x > 0.f ? o0.x : 0.2f * o0.x;
      o0.y = o0.y > 0.f ? o0.y : 0.2f * o0.y;
      o0.z = o0.z > 0.f ? o0.z : 0.2f * o0.z;
      o0.w = o0.w > 0.f ? o0.w : 0.2f * o0.w;
      o1.x = o1.x > 0.f ? o1.x : 0.2f * o1.x;
      o1.y = o1.y > 0.f ? o1.y : 0.2f * o1.y;
      o1.z = o1.z > 0.f ? o1.z : 0.2f * o1.z;
      o1.w = o1.w > 0.f ? o1.w : 0.2f * o1.w;
      if (SCALE_OUT) {
        o0.x *= nrm; o0.y *= nrm; o0.z *= nrm; o0.w *= nrm;
        o1.x *= nrm; o1.y *= nrm; o1.z *= nrm; o1.w *= nrm;
      }
      float4* op = reinterpret_cast<float4*>(out + (size_t)row * H + half * 64 + j8 * 8);
      op[0] = o0;
      op[1] = o1;
    }
  }
}

}  // namespace

extern "C" void kernel_launch(void* const* d_in, const int* in_sizes, int n_in,
                              void* d_out, int out_size, void* d_ws, size_t ws_size,
                              hipStream_t stream) {
  float* out = (float*)d_out;                 // OUTPUT IS FP32
  const int nElem = NN * H;                   // 12.8M
  const int mkBl  = (out_size + 255) / 256;

  bool order_ok =
      (n_in == 9 && in_sizes[0] == NN && in_sizes[1] == NE && in_sizes[2] == NE &&
       in_sizes[3] == NN && in_sizes[4] == NN * H && in_sizes[5] == H * H &&
       in_sizes[6] == H && in_sizes[7] == H * H && in_sizes[8] == H);
  if (!order_ok || out_size != nElem) {
    write_marker<<<mkBl, 256, 0, stream>>>(out, out_size,
                                           (out_size != nElem) ? 300.0f : 200.0f);
    return;
  }
  if (ws_size < (size_t)nElem * 4) {
    write_marker<<<mkBl, 256, 0, stream>>>(out, out_size,
                                           2.0f + (float)(ws_size >> 20));
    return;
  }

  const int* node_id = (const int*)d_in[0];
  const int* src     = (const int*)d_in[1];
  const int* dst     = (const int*)d_in[2];
  const float* norm  = (const float*)d_in[3];
  const float* embed = (const float*)d_in[4];
  const float* W1    = (const float*)d_in[5];
  const float* b1    = (const float*)d_in[6];
  const float* W2    = (const float*)d_in[7];
  const float* b2    = (const float*)d_in[8];

  float* agg = (float*)d_ws;                             // 51.2 MB
  float* h1n = out;                                      // d_out holds h1*norm
  int2* rec1 = (int2*)((char*)d_ws + (size_t)nElem * 4); // NE x 8B (8-aligned)
  int* csr2  = (int*)(rec1 + NE);                        // NE
  int* offs  = csr2 + NE;                                // NN+1
  int* cnt   = offs + (NN + 1);                          // NN
  int* bsums = cnt + NN;                                 // 512

  const size_t need_mid =
      (size_t)nElem * 4 + ((size_t)NE + (NN + 1) + NN + 512) * 4;        // ~54.4 MB
  const size_t need_full = need_mid + (size_t)NE * 8;                    // ~59.2 MB

  const int zeroNBl = (NN + 255) / 256;
  const int edgeBl  = (NE + 255) / 256;

  if (ws_size >= need_mid) {
    const bool full = (ws_size >= need_full);
    // layout shift for mid tier: rec1 unused; csr2 right after agg
    if (!full) {
      csr2  = (int*)((char*)d_ws + (size_t)nElem * 4);
      offs  = csr2 + NE;
      cnt   = offs + (NN + 1);
      bsums = cnt + NN;
    }

    // ---- build CSR by dst (shared by both layers) ----
    zero_int<<<zeroNBl, 256, 0, stream>>>(cnt, NN);
    hist_dst<<<edgeBl, 256, 0, stream>>>(dst, cnt);
    scan1<<<NBLK_SCAN, SCAN_B, 0, stream>>>(cnt, offs, bsums);
    scan2<<<1, 512, 0, stream>>>(bsums);
    scan3<<<NBLK_SCAN, 256, 0, stream>>>(offs, bsums, cnt);
    if (full)
      fill_csr<true><<<edgeBl, 256, 0, stream>>>(src, dst, node_id, norm, cnt, csr2, rec1);
    else
      fill_csr<false><<<edgeBl, 256, 0, stream>>>(src, dst, node_id, norm, cnt, csr2, nullptr);

    // ---- layer 1 ----
    if (full)
      gather_rec<<<NN / 8, 256, 0, stream>>>(offs, rec1, embed, agg);
    else
      gather_mid_l1<<<NN / 8, 256, 0, stream>>>(offs, csr2, node_id, embed, norm, agg);
    gemm_v8<true><<<NROWBLK256 * 2, 256, 0, stream>>>(agg, W1, norm, b1, h1n);

    // ---- layer 2 ----
    gather_idx<<<NN / 8, 256, 0, stream>>>(offs, csr2, h1n, agg);
    gemm_v8<false><<<NROWBLK256 * 2, 256, 0, stream>>>(agg, W2, norm, b2, out);
    return;
  }

  // ---- bottom-tier fallback: atomic path ----
  const int zeroBl = (nElem / 4 + 255) / 256;
  const int scatBl = (NE * 32 + 255) / 256;

  zero_f4<<<zeroBl, 256, 0, stream>>>((float4*)agg, nElem / 4);
  scatter_l1<<<scatBl, 256, 0, stream>>>(src, dst, node_id, embed, norm, agg);
  row_gemm_act<<<NN, 128, 0, stream>>>(agg, W1, norm, b1, out);

  zero_f4<<<zeroBl, 256, 0, stream>>>((float4*)agg, nElem / 4);
  scatter_l2<<<scatBl, 256, 0, stream>>>(src, dst, out, norm, agg);
  row_gemm_act<<<NN, 128, 0, stream>>>(agg, W2, norm, b2, out);
}

// Round 12
// 368.290 us; speedup vs baseline: 1.1859x; 1.1859x over previous
//
#include <hip/hip_runtime.h>

namespace {
constexpr int NN = 100000;
constexpr int NE = 600000;
constexpr int H  = 128;
constexpr int SCAN_B = 256;
constexpr int NBLK_SCAN = (NN + SCAN_B - 1) / SCAN_B;  // 391
constexpr int NROWBLK = (NN + 127) / 128;              // 782

__global__ __launch_bounds__(256) void write_marker(float* __restrict__ out,
                                                    int n, float val) {
  int i = blockIdx.x * 256 + threadIdx.x;
  if (i < n) out[i] = val;
}

// ---------------- bottom-tier fallback (atomic path, verified) ----------------

__global__ __launch_bounds__(256) void zero_f4(float4* __restrict__ p, int n4) {
  int i = blockIdx.x * 256 + threadIdx.x;
  if (i < n4) p[i] = float4{0.f, 0.f, 0.f, 0.f};
}

__global__ __launch_bounds__(256) void scatter_l1(
    const int* __restrict__ src, const int* __restrict__ dst,
    const int* __restrict__ node_id, const float* __restrict__ embed,
    const float* __restrict__ norm, float* __restrict__ agg) {
  int idx = blockIdx.x * 256 + threadIdx.x;
  int e = idx >> 5;
  if (e >= NE) return;
  int c = (idx & 31) << 2;
  int s = src[e];
  float nrm = norm[s];
  const float4 v = *reinterpret_cast<const float4*>(embed + (size_t)node_id[s] * H + c);
  float* o = agg + (size_t)dst[e] * H + c;
  atomicAdd(o + 0, v.x * nrm);
  atomicAdd(o + 1, v.y * nrm);
  atomicAdd(o + 2, v.z * nrm);
  atomicAdd(o + 3, v.w * nrm);
}

__global__ __launch_bounds__(256) void scatter_l2(
    const int* __restrict__ src, const int* __restrict__ dst,
    const float* __restrict__ h1, const float* __restrict__ norm,
    float* __restrict__ agg) {
  int idx = blockIdx.x * 256 + threadIdx.x;
  int e = idx >> 5;
  if (e >= NE) return;
  int c = (idx & 31) << 2;
  int s = src[e];
  float nrm = norm[s];
  const float4 v = *reinterpret_cast<const float4*>(h1 + (size_t)s * H + c);
  float* o = agg + (size_t)dst[e] * H + c;
  atomicAdd(o + 0, v.x * nrm);
  atomicAdd(o + 1, v.y * nrm);
  atomicAdd(o + 2, v.z * nrm);
  atomicAdd(o + 3, v.w * nrm);
}

__global__ __launch_bounds__(128) void row_gemm_act(
    const float* __restrict__ agg, const float* __restrict__ W,
    const float* __restrict__ norm, const float* __restrict__ bias,
    float* __restrict__ out) {
  __shared__ float hs[H];
  const int row = blockIdx.x, j = threadIdx.x;
  hs[j] = agg[(size_t)row * H + j];
  __syncthreads();
  float acc = 0.f;
#pragma unroll
  for (int k = 0; k < H; ++k) acc += hs[k] * W[k * H + j];
  float v = acc * norm[row] + bias[j];
  v = v > 0.f ? v : 0.2f * v;
  out[(size_t)row * H + j] = v;
}

// ---------------- CSR build ----------------

__global__ __launch_bounds__(256) void zero_int(int* __restrict__ p, int n) {
  int i = blockIdx.x * 256 + threadIdx.x;
  if (i < n) p[i] = 0;
}

__global__ __launch_bounds__(256) void hist_dst(const int* __restrict__ dst,
                                                int* __restrict__ deg) {
  int e = blockIdx.x * 256 + threadIdx.x;
  if (e < NE) atomicAdd(&deg[dst[e]], 1);
}

__global__ __launch_bounds__(SCAN_B) void scan1(const int* __restrict__ deg,
                                                int* __restrict__ offs,
                                                int* __restrict__ bsums) {
  __shared__ int sh[SCAN_B];
  const int t = threadIdx.x;
  const int gid = blockIdx.x * SCAN_B + t;
  int v = (gid < NN) ? deg[gid] : 0;
  sh[t] = v;
  __syncthreads();
  for (int d = 1; d < SCAN_B; d <<= 1) {
    int add = (t >= d) ? sh[t - d] : 0;
    __syncthreads();
    sh[t] += add;
    __syncthreads();
  }
  if (gid < NN) offs[gid] = sh[t] - v;
  if (t == SCAN_B - 1) bsums[blockIdx.x] = sh[t];
}

// merged scan2+scan3: each block reduces bsums[0..bid) itself, adds to offs,
// seeds cnt = offs. One fewer serialized launch than separate scan2/scan3.
__global__ __launch_bounds__(256) void scan23(int* __restrict__ offs,
                                              const int* __restrict__ bsums,
                                              int* __restrict__ cnt) {
  __shared__ int sh[256];
  const int t = threadIdx.x;
  const int bid = blockIdx.x;
  // partial sums of bsums[j] for j < bid (NBLK_SCAN=391 <= 512)
  int p = 0;
  if (t < bid) p += bsums[t];
  if (t + 256 < bid) p += bsums[t + 256];
  sh[t] = p;
  __syncthreads();
#pragma unroll
  for (int d = 128; d > 0; d >>= 1) {
    if (t < d) sh[t] += sh[t + d];
    __syncthreads();
  }
  const int base = sh[0];
  const int gid = bid * 256 + t;
  if (gid < NN) {
    int v = offs[gid] + base;
    offs[gid] = v;
    cnt[gid] = v;
  }
  if (gid == 0) offs[NN] = NE;
}

template <bool WITH_REC>
__global__ __launch_bounds__(256) void fill_csr(
    const int* __restrict__ src, const int* __restrict__ dst,
    const int* __restrict__ node_id, const float* __restrict__ norm,
    int* __restrict__ cnt, int* __restrict__ csr2, int2* __restrict__ rec1) {
  int e = blockIdx.x * 256 + threadIdx.x;
  if (e >= NE) return;
  int d = dst[e];
  int s = src[e];
  int pos = atomicAdd(&cnt[d], 1);
  csr2[pos] = s;
  if (WITH_REC) rec1[pos] = make_int2(node_id[s], __float_as_int(norm[s]));
}

// ---------------- gathers (no atomics; 4-way independent chains for MLP) ----------------

// L1: per-edge record {row, nrm}; 32 lanes per node, float4/lane.
__global__ __launch_bounds__(256) void gather_rec(
    const int* __restrict__ offs, const int2* __restrict__ rec,
    const float* __restrict__ h, float* __restrict__ agg) {
  const int node = blockIdx.x * 8 + (threadIdx.x >> 5);
  const int c = (threadIdx.x & 31) << 2;
  const int beg = offs[node];
  const int end = offs[node + 1];
  float4 a0{0,0,0,0}, a1{0,0,0,0}, a2{0,0,0,0}, a3{0,0,0,0};
  int i = beg;
  for (; i + 4 <= end; i += 4) {
    int2 r0 = rec[i], r1 = rec[i + 1], r2 = rec[i + 2], r3 = rec[i + 3];
    const float4 v0 = *reinterpret_cast<const float4*>(h + (size_t)r0.x * H + c);
    const float4 v1 = *reinterpret_cast<const float4*>(h + (size_t)r1.x * H + c);
    const float4 v2 = *reinterpret_cast<const float4*>(h + (size_t)r2.x * H + c);
    const float4 v3 = *reinterpret_cast<const float4*>(h + (size_t)r3.x * H + c);
    float n0 = __int_as_float(r0.y), n1 = __int_as_float(r1.y);
    float n2 = __int_as_float(r2.y), n3 = __int_as_float(r3.y);
    a0.x += v0.x * n0; a0.y += v0.y * n0; a0.z += v0.z * n0; a0.w += v0.w * n0;
    a1.x += v1.x * n1; a1.y += v1.y * n1; a1.z += v1.z * n1; a1.w += v1.w * n1;
    a2.x += v2.x * n2; a2.y += v2.y * n2; a2.z += v2.z * n2; a2.w += v2.w * n2;
    a3.x += v3.x * n3; a3.y += v3.y * n3; a3.z += v3.z * n3; a3.w += v3.w * n3;
  }
  for (; i < end; ++i) {
    int2 r0 = rec[i];
    const float4 v0 = *reinterpret_cast<const float4*>(h + (size_t)r0.x * H + c);
    float n0 = __int_as_float(r0.y);
    a0.x += v0.x * n0; a0.y += v0.y * n0; a0.z += v0.z * n0; a0.w += v0.w * n0;
  }
  a0.x += a1.x + a2.x + a3.x;
  a0.y += a1.y + a2.y + a3.y;
  a0.z += a1.z + a2.z + a3.z;
  a0.w += a1.w + a2.w + a3.w;
  *reinterpret_cast<float4*>(agg + (size_t)node * H + c) = a0;
}

// L2: h is pre-scaled by norm (h1n), so just sum rows.
__global__ __launch_bounds__(256) void gather_idx(
    const int* __restrict__ offs, const int* __restrict__ csr,
    const float* __restrict__ h, float* __restrict__ agg) {
  const int node = blockIdx.x * 8 + (threadIdx.x >> 5);
  const int c = (threadIdx.x & 31) << 2;
  const int beg = offs[node];
  const int end = offs[node + 1];
  float4 a0{0,0,0,0}, a1{0,0,0,0}, a2{0,0,0,0}, a3{0,0,0,0};
  int i = beg;
  for (; i + 4 <= end; i += 4) {
    int s0 = csr[i], s1 = csr[i + 1], s2 = csr[i + 2], s3 = csr[i + 3];
    const float4 v0 = *reinterpret_cast<const float4*>(h + (size_t)s0 * H + c);
    const float4 v1 = *reinterpret_cast<const float4*>(h + (size_t)s1 * H + c);
    const float4 v2 = *reinterpret_cast<const float4*>(h + (size_t)s2 * H + c);
    const float4 v3 = *reinterpret_cast<const float4*>(h + (size_t)s3 * H + c);
    a0.x += v0.x; a0.y += v0.y; a0.z += v0.z; a0.w += v0.w;
    a1.x += v1.x; a1.y += v1.y; a1.z += v1.z; a1.w += v1.w;
    a2.x += v2.x; a2.y += v2.y; a2.z += v2.z; a2.w += v2.w;
    a3.x += v3.x; a3.y += v3.y; a3.z += v3.z; a3.w += v3.w;
  }
  for (; i < end; ++i) {
    int s0 = csr[i];
    const float4 v0 = *reinterpret_cast<const float4*>(h + (size_t)s0 * H + c);
    a0.x += v0.x; a0.y += v0.y; a0.z += v0.z; a0.w += v0.w;
  }
  a0.x += a1.x + a2.x + a3.x;
  a0.y += a1.y + a2.y + a3.y;
  a0.z += a1.z + a2.z + a3.z;
  a0.w += a1.w + a2.w + a3.w;
  *reinterpret_cast<float4*>(agg + (size_t)node * H + c) = a0;
}

// mid-tier L1 gather (no records): loads node_id/norm per edge
__global__ __launch_bounds__(256) void gather_mid_l1(
    const int* __restrict__ offs, const int* __restrict__ csr,
    const int* __restrict__ node_id, const float* __restrict__ h,
    const float* __restrict__ norm, float* __restrict__ agg) {
  const int node = blockIdx.x * 8 + (threadIdx.x >> 5);
  const int c = (threadIdx.x & 31) << 2;
  const int beg = offs[node];
  const int end = offs[node + 1];
  float4 acc{0.f, 0.f, 0.f, 0.f};
  for (int i = beg; i < end; ++i) {
    int s = csr[i];
    float nrm = norm[s];
    const float4 v = *reinterpret_cast<const float4*>(h + (size_t)node_id[s] * H + c);
    acc.x += v.x * nrm; acc.y += v.y * nrm; acc.z += v.z * nrm; acc.w += v.w * nrm;
  }
  *reinterpret_cast<float4*>(agg + (size_t)node * H + c) = acc;
}

// ---------------- GEMM v7 (PROVEN 54.5 us/layer, r10) — reverted after v8 regression ----------------
// v8 post-mortem (r11): 256-row tile -> compiler kept only accumulators
// (VGPR 72), re-fetched A (FETCH 52->203 MB, 4x A), L2 thrash -> 88-93 us.
// v7 remains the best measured: 32 KB W-half in LDS, 128 rows x 64 cols,
// 4 rows/thread, register double-buffered A prefetch. VALUBusy ~49% plateau.

#define FMA4(ACC, S, W) \
  ACC.x += (S) * (W).x; ACC.y += (S) * (W).y; ACC.z += (S) * (W).z; ACC.w += (S) * (W).w;

#define FMAROW(ACCA, ACCB, AV)                  \
  FMA4(ACCA, AV.x, wa0) FMA4(ACCB, AV.x, wb0)   \
  FMA4(ACCA, AV.y, wa1) FMA4(ACCB, AV.y, wb1)   \
  FMA4(ACCA, AV.z, wa2) FMA4(ACCB, AV.z, wb2)   \
  FMA4(ACCA, AV.w, wa3) FMA4(ACCB, AV.w, wb3)

#define WLOADS(KB)                                                        \
  float4 wa0 = Wld[(KB) + 2 * j8],      wb0 = Wld[(KB) + 2 * j8 + 1];     \
  float4 wa1 = Wld[(KB) + 16 + 2 * j8], wb1 = Wld[(KB) + 16 + 2 * j8 + 1];\
  float4 wa2 = Wld[(KB) + 32 + 2 * j8], wb2 = Wld[(KB) + 32 + 2 * j8 + 1];\
  float4 wa3 = Wld[(KB) + 48 + 2 * j8], wb3 = Wld[(KB) + 48 + 2 * j8 + 1];

// out[row] = LReLU((agg[row] @ W) * norm[row] + b) * (SCALE_OUT ? norm[row] : 1)
template <bool SCALE_OUT>
__global__ __launch_bounds__(256, 3) void gemm_v7(
    const float* __restrict__ agg, const float* __restrict__ W,
    const float* __restrict__ norm, const float* __restrict__ bias,
    float* __restrict__ out) {
  __shared__ float4 Wld[128 * 16];  // 32 KB: [k][c], c=0..15 -> col half*64+c*4
  const int t = threadIdx.x;
  const int half = blockIdx.x & 1;           // column half (0: cols 0-63, 1: 64-127)
  const int rowBase = (blockIdx.x >> 1) * 128;

  // stage W half: 2048 float4, 8 per thread
  const float4* W4 = reinterpret_cast<const float4*>(W);
#pragma unroll
  for (int i = 0; i < 8; ++i) {
    int g = t + i * 256;            // 0..2047
    int k = g >> 4, c = g & 15;
    Wld[k * 16 + c] = W4[k * 32 + half * 16 + c];
  }
  __syncthreads();

  const int j8 = t & 7;    // col group of 8 within half
  const int r0 = t >> 3;   // 0..31; rows r0 + 32*i, i=0..3
  const float4* A4 = reinterpret_cast<const float4*>(agg) + (size_t)rowBase * 32;
  // per-row streaming pointers (A row stride = 32 float4)
  const float4* ap0 = A4 + (size_t)(r0 +  0) * 32;
  const float4* ap1 = A4 + (size_t)(r0 + 32) * 32;
  const float4* ap2 = A4 + (size_t)(r0 + 64) * 32;
  const float4* ap3 = A4 + (size_t)(r0 + 96) * 32;

  float4 accA[4], accB[4];
#pragma unroll
  for (int i = 0; i < 4; ++i) {
    accA[i] = float4{0.f, 0.f, 0.f, 0.f};
    accB[i] = float4{0.f, 0.f, 0.f, 0.f};
  }

  // NOTE: last row-block reads A rows up to 100095 (> NN); those land inside
  // the allocated workspace (CSR arrays follow agg) so reads are safe; the
  // corresponding outputs are guarded at the store.
  float4 c0 = ap0[0], c1 = ap1[0], c2 = ap2[0], c3 = ap3[0];

#pragma unroll 4
  for (int k4 = 0; k4 < 31; ++k4) {
    // prefetch next k4 (waitcnt consumed at the swap below -> hidden by FMAs)
    float4 n0 = ap0[k4 + 1], n1 = ap1[k4 + 1], n2 = ap2[k4 + 1], n3 = ap3[k4 + 1];
    WLOADS(k4 * 64)
    FMAROW(accA[0], accB[0], c0)
    FMAROW(accA[1], accB[1], c1)
    FMAROW(accA[2], accB[2], c2)
    FMAROW(accA[3], accB[3], c3)
    c0 = n0; c1 = n1; c2 = n2; c3 = n3;
  }
  {  // k4 = 31 (no prefetch)
    WLOADS(31 * 64)
    FMAROW(accA[0], accB[0], c0)
    FMAROW(accA[1], accB[1], c1)
    FMAROW(accA[2], accB[2], c2)
    FMAROW(accA[3], accB[3], c3)
  }

  const float4 bv0 = reinterpret_cast<const float4*>(bias)[half * 16 + 2 * j8];
  const float4 bv1 = reinterpret_cast<const float4*>(bias)[half * 16 + 2 * j8 + 1];
#pragma unroll
  for (int i = 0; i < 4; ++i) {
    const int row = rowBase + r0 + 32 * i;
    if (row < NN) {
      const float nrm = norm[row];
      float4 o0, o1;
      o0.x = accA[i].x * nrm + bv0.x; o0.y = accA[i].y * nrm + bv0.y;
      o0.z = accA[i].z * nrm + bv0.z; o0.w = accA[i].w * nrm + bv0.w;
      o1.x = accB[i].x * nrm + bv1.x; o1.y = accB[i].y * nrm + bv1.y;
      o1.z = accB[i].z * nrm + bv1.z; o1.w = accB[i].w * nrm + bv1.w;
      o0.x = o0.x > 0.f ? o0.x : 0.2f * o0.x;
      o0.y = o0.y > 0.f ? o0.y : 0.2f * o0.y;
      o0.z = o0.z > 0.f ? o0.z : 0.2f * o0.z;
      o0.w = o0.w > 0.f ? o0.w : 0.2f * o0.w;
      o1.x = o1.x > 0.f ? o1.x : 0.2f * o1.x;
      o1.y = o1.y > 0.f ? o1.y : 0.2f * o1.y;
      o1.z = o1.z > 0.f ? o1.z : 0.2f * o1.z;
      o1.w = o1.w > 0.f ? o1.w : 0.2f * o1.w;
      if (SCALE_OUT) {
        o0.x *= nrm; o0.y *= nrm; o0.z *= nrm; o0.w *= nrm;
        o1.x *= nrm; o1.y *= nrm; o1.z *= nrm; o1.w *= nrm;
      }
      float4* op = reinterpret_cast<float4*>(out + (size_t)row * H + half * 64 + j8 * 8);
      op[0] = o0;
      op[1] = o1;
    }
  }
}

}  // namespace

extern "C" void kernel_launch(void* const* d_in, const int* in_sizes, int n_in,
                              void* d_out, int out_size, void* d_ws, size_t ws_size,
                              hipStream_t stream) {
  float* out = (float*)d_out;                 // OUTPUT IS FP32
  const int nElem = NN * H;                   // 12.8M
  const int mkBl  = (out_size + 255) / 256;

  bool order_ok =
      (n_in == 9 && in_sizes[0] == NN && in_sizes[1] == NE && in_sizes[2] == NE &&
       in_sizes[3] == NN && in_sizes[4] == NN * H && in_sizes[5] == H * H &&
       in_sizes[6] == H && in_sizes[7] == H * H && in_sizes[8] == H);
  if (!order_ok || out_size != nElem) {
    write_marker<<<mkBl, 256, 0, stream>>>(out, out_size,
                                           (out_size != nElem) ? 300.0f : 200.0f);
    return;
  }
  if (ws_size < (size_t)nElem * 4) {
    write_marker<<<mkBl, 256, 0, stream>>>(out, out_size,
                                           2.0f + (float)(ws_size >> 20));
    return;
  }

  const int* node_id = (const int*)d_in[0];
  const int* src     = (const int*)d_in[1];
  const int* dst     = (const int*)d_in[2];
  const float* norm  = (const float*)d_in[3];
  const float* embed = (const float*)d_in[4];
  const float* W1    = (const float*)d_in[5];
  const float* b1    = (const float*)d_in[6];
  const float* W2    = (const float*)d_in[7];
  const float* b2    = (const float*)d_in[8];

  float* agg = (float*)d_ws;                             // 51.2 MB
  float* h1n = out;                                      // d_out holds h1*norm
  int2* rec1 = (int2*)((char*)d_ws + (size_t)nElem * 4); // NE x 8B (8-aligned)
  int* csr2  = (int*)(rec1 + NE);                        // NE
  int* offs  = csr2 + NE;                                // NN+1
  int* cnt   = offs + (NN + 1);                          // NN
  int* bsums = cnt + NN;                                 // 512

  const size_t need_mid =
      (size_t)nElem * 4 + ((size_t)NE + (NN + 1) + NN + 512) * 4;        // ~54.4 MB
  const size_t need_full = need_mid + (size_t)NE * 8;                    // ~59.2 MB

  const int zeroNBl = (NN + 255) / 256;
  const int edgeBl  = (NE + 255) / 256;

  if (ws_size >= need_mid) {
    const bool full = (ws_size >= need_full);
    // layout shift for mid tier: rec1 unused; csr2 right after agg
    if (!full) {
      csr2  = (int*)((char*)d_ws + (size_t)nElem * 4);
      offs  = csr2 + NE;
      cnt   = offs + (NN + 1);
      bsums = cnt + NN;
    }

    // ---- build CSR by dst (shared by both layers) ----
    zero_int<<<zeroNBl, 256, 0, stream>>>(cnt, NN);
    hist_dst<<<edgeBl, 256, 0, stream>>>(dst, cnt);
    scan1<<<NBLK_SCAN, SCAN_B, 0, stream>>>(cnt, offs, bsums);
    scan23<<<NBLK_SCAN, 256, 0, stream>>>(offs, bsums, cnt);
    if (full)
      fill_csr<true><<<edgeBl, 256, 0, stream>>>(src, dst, node_id, norm, cnt, csr2, rec1);
    else
      fill_csr<false><<<edgeBl, 256, 0, stream>>>(src, dst, node_id, norm, cnt, csr2, nullptr);

    // ---- layer 1 ----
    if (full)
      gather_rec<<<NN / 8, 256, 0, stream>>>(offs, rec1, embed, agg);
    else
      gather_mid_l1<<<NN / 8, 256, 0, stream>>>(offs, csr2, node_id, embed, norm, agg);
    gemm_v7<true><<<NROWBLK * 2, 256, 0, stream>>>(agg, W1, norm, b1, h1n);

    // ---- layer 2 ----
    gather_idx<<<NN / 8, 256, 0, stream>>>(offs, csr2, h1n, agg);
    gemm_v7<false><<<NROWBLK * 2, 256, 0, stream>>>(agg, W2, norm, b2, out);
    return;
  }

  // ---- bottom-tier fallback: atomic path ----
  const int zeroBl = (nElem / 4 + 255) / 256;
  const int scatBl = (NE * 32 + 255) / 256;

  zero_f4<<<zeroBl, 256, 0, stream>>>((float4*)agg, nElem / 4);
  scatter_l1<<<scatBl, 256, 0, stream>>>(src, dst, node_id, embed, norm, agg);
  row_gemm_act<<<NN, 128, 0, stream>>>(agg, W1, norm, b1, out);

  zero_f4<<<zeroBl, 256, 0, stream>>>((float4*)agg, nElem / 4);
  scatter_l2<<<scatBl, 256, 0, stream>>>(src, dst, out, norm, agg);
  row_gemm_act<<<NN, 128, 0, stream>>>(agg, W2, norm, b2, out);
}